// Round 1
// baseline (482.219 us; speedup 1.0000x reference)
//
#include <hip/hip_runtime.h>

// EMD via Sinkhorn on 64 Hamming states.
// Key structure: K = exp(-C/eps), C = Hamming over 6 bits
//   => K = tensor product of six 2x2 [[1,a],[a,1]], a = exp(-10).
//   => u@K is 6 butterfly stages: new[i] = w[i] + a*w[i^bit].
// EMD readout: with w = K v, u = p/w:
//   emd = (a * sum_b u.X_b w  -  6 a^2 * u.w) / (1 - a^2),  X_b = bit-b swap.
// One thread per batch row; p/q/w arrays fully in VGPRs (all indices constant).

namespace {

constexpr int   N     = 64;
constexpr int   NBITS = 6;
constexpr int   ITERS = 50;
constexpr float TINY  = 1e-8f;

constexpr double Ad = 4.5399929762484854e-05;           // exp(-10)
constexpr float  A  = (float)Ad;
// 1 / (1+a)^6  -- row sum of K is (1+a)^6 (regular graph), used for the
// first half-step where u = ones.
constexpr double ROWSUM6 = (1.0 + Ad) * (1.0 + Ad) * (1.0 + Ad) *
                           (1.0 + Ad) * (1.0 + Ad) * (1.0 + Ad);
constexpr float  C0 = (float)(1.0 / ROWSUM6);
constexpr float  EMD_SCALE = (float)(Ad / (1.0 - Ad * Ad));
constexpr float  EMD_DIAG  = (float)(6.0 * Ad * Ad / (1.0 - Ad * Ad));

__device__ __forceinline__ float rcp(float x) { return __builtin_amdgcn_rcpf(x); }

// In-place w <- K w  (K symmetric, so this serves both u@K and v@K^T).
__device__ __forceinline__ void butterfly(float w[N]) {
#pragma unroll
  for (int b = 0; b < NBITS; ++b) {
#pragma unroll
    for (int i = 0; i < N; ++i) {
      if ((i & (1 << b)) == 0) {
        const int j = i | (1 << b);
        const float wi = w[i];
        const float wj = w[j];
        w[i] = fmaf(A, wj, wi);
        w[j] = fmaf(A, wi, wj);
      }
    }
  }
}

__global__ __launch_bounds__(256, 2) void emd_sinkhorn_kernel(
    const float* __restrict__ gp, const float* __restrict__ gq,
    float* __restrict__ out, int nbatch) {
  const int b = blockIdx.x * 256 + threadIdx.x;
  if (b >= nbatch) return;

  float p[N], q[N], w[N];

  const float4* __restrict__ p4 =
      reinterpret_cast<const float4*>(gp) + (size_t)b * (N / 4);
  const float4* __restrict__ q4 =
      reinterpret_cast<const float4*>(gq) + (size_t)b * (N / 4);

  // Load + epsilon-smooth + accumulate sums.
  float ps = 0.f, qs = 0.f;
#pragma unroll
  for (int k = 0; k < N / 4; ++k) {
    const float4 tp = p4[k];
    p[4 * k + 0] = tp.x + TINY;
    p[4 * k + 1] = tp.y + TINY;
    p[4 * k + 2] = tp.z + TINY;
    p[4 * k + 3] = tp.w + TINY;
    const float4 tq = q4[k];
    q[4 * k + 0] = tq.x + TINY;
    q[4 * k + 1] = tq.y + TINY;
    q[4 * k + 2] = tq.z + TINY;
    q[4 * k + 3] = tq.w + TINY;
  }
#pragma unroll
  for (int i = 0; i < N; ++i) { ps += p[i]; qs += q[i]; }
  const float rp = rcp(ps);
  const float rq = rcp(qs);
#pragma unroll
  for (int i = 0; i < N; ++i) { p[i] *= rp; q[i] *= rq; }

  // Iter 1 first half: u0 = ones => u0@K = (1+a)^6 * ones => v1 = q / rowsum.
#pragma unroll
  for (int i = 0; i < N; ++i) w[i] = q[i] * C0;

  // Remaining 49 full iterations; each: u_k = p/(K v_k); v_{k+1} = q/(K u_k).
#pragma unroll 1
  for (int it = 0; it < ITERS - 1; ++it) {
    butterfly(w);  // K v_k
#pragma unroll
    for (int i = 0; i < N; ++i) w[i] = p[i] * rcp(w[i]);  // u_k
    butterfly(w);  // K u_k
#pragma unroll
    for (int i = 0; i < N; ++i) w[i] = q[i] * rcp(w[i]);  // v_{k+1}
  }

  // Final: w = K v_50 ; u_50 = p / w (formed on the fly in the epilogue).
  butterfly(w);

  float s0 = 0.f;  // u . w           (== sum p == 1, but compute numerically)
  float sx = 0.f;  // sum_b u . X_b w
#pragma unroll
  for (int i = 0; i < N; ++i) {
    const float ui = p[i] * rcp(w[i]);
    s0 = fmaf(ui, w[i], s0);
#pragma unroll
    for (int bb = 0; bb < NBITS; ++bb) {
      sx = fmaf(ui, w[i ^ (1 << bb)], sx);
    }
  }

  out[b] = sx * EMD_SCALE - s0 * EMD_DIAG;
}

}  // namespace

extern "C" void kernel_launch(void* const* d_in, const int* in_sizes, int n_in,
                              void* d_out, int out_size, void* d_ws, size_t ws_size,
                              hipStream_t stream) {
  const float* p = (const float*)d_in[0];
  const float* q = (const float*)d_in[1];
  // d_in[2] is the Hamming cost matrix; its structure is hardcoded above.
  float* out = (float*)d_out;

  const int nbatch = in_sizes[0] / N;  // 262144
  const int block = 256;
  const int grid = (nbatch + block - 1) / block;
  emd_sinkhorn_kernel<<<grid, block, 0, stream>>>(p, q, out, nbatch);
}